// Round 1
// baseline (4047.127 us; speedup 1.0000x reference)
//
#include <hip/hip_runtime.h>
#include <math.h>

#define NN 10000
#define NE 20000
#define FIN 128
#define NHEAD 8
#define C1 512
#define C2 256
#define NB 64
#define NOUT 10

// monotone float<->uint encoding for atomic max on floats
__device__ __forceinline__ unsigned enc_f(float f) {
    unsigned u = __float_as_uint(f);
    return (u & 0x80000000u) ? ~u : (u | 0x80000000u);
}
__device__ __forceinline__ float dec_f(unsigned e) {
    return (e & 0x80000000u) ? __uint_as_float(e & 0x7fffffffu) : __uint_as_float(~e);
}

// ---- tiled fp32 GEMM with bias: C[M, ncols] = A[M,K] @ B[K, ncols] + bias ----
// grid: (ncols/64, ceil(M/64)), block: 256 flat. K % 16 == 0, ncols % 64 == 0.
__global__ __launch_bounds__(256) void gemm_bias(
    const float* __restrict__ A, int lda,
    const float* __restrict__ B, int ldb,
    const float* __restrict__ bias,
    float* __restrict__ C, int ldc,
    int M, int K)
{
    __shared__ float As[16][65];
    __shared__ float Bs[16][68];
    const int t  = threadIdx.x;
    const int m0 = blockIdx.y * 64;
    const int n0 = blockIdx.x * 64;
    float acc[4][4] = {};
    const int ar = t >> 2, ak = (t & 3) << 2;   // A tile: 64 rows x 16 k
    const int bk = t >> 4, bn = (t & 15) << 2;  // B tile: 16 k x 64 cols

    for (int k0 = 0; k0 < K; k0 += 16) {
        float4 av = make_float4(0.f, 0.f, 0.f, 0.f);
        int row = m0 + ar;
        if (row < M) av = *(const float4*)(A + (size_t)row * lda + k0 + ak);
        As[ak+0][ar] = av.x; As[ak+1][ar] = av.y; As[ak+2][ar] = av.z; As[ak+3][ar] = av.w;
        float4 bv = *(const float4*)(B + (size_t)(k0 + bk) * ldb + n0 + bn);
        Bs[bk][bn+0] = bv.x; Bs[bk][bn+1] = bv.y; Bs[bk][bn+2] = bv.z; Bs[bk][bn+3] = bv.w;
        __syncthreads();
        #pragma unroll
        for (int kk = 0; kk < 16; ++kk) {
            float a[4], b[4];
            #pragma unroll
            for (int i = 0; i < 4; ++i) a[i] = As[kk][(t >> 4) * 4 + i];
            #pragma unroll
            for (int j = 0; j < 4; ++j) b[j] = Bs[kk][(t & 15) * 4 + j];
            #pragma unroll
            for (int i = 0; i < 4; ++i)
                #pragma unroll
                for (int j = 0; j < 4; ++j)
                    acc[i][j] = fmaf(a[i], b[j], acc[i][j]);
        }
        __syncthreads();
    }
    const int col = n0 + (t & 15) * 4;
    #pragma unroll
    for (int i = 0; i < 4; ++i) {
        int row = m0 + (t >> 4) * 4 + i;
        if (row < M) {
            float4 r;
            r.x = acc[i][0] + bias[col + 0];
            r.y = acc[i][1] + bias[col + 1];
            r.z = acc[i][2] + bias[col + 2];
            r.w = acc[i][3] + bias[col + 3];
            *(float4*)(C + (size_t)row * ldc + col) = r;
        }
    }
}

__global__ void init_seg(unsigned* __restrict__ amax, float* __restrict__ denom, int n) {
    int i = blockIdx.x * blockDim.x + threadIdx.x;
    if (i < n) { amax[i] = 0x007FFFFFu; denom[i] = 0.f; }  // enc(-inf)
}

__global__ void init_pool(unsigned* __restrict__ amax, float* __restrict__ denom,
                          float* __restrict__ g) {
    int i = blockIdx.x * blockDim.x + threadIdx.x;
    if (i < NB) { amax[i] = 0x007FFFFFu; denom[i] = 0.f; }
    if (i < NB * C2) g[i] = 0.f;
}

// one wave (64 lanes) per edge: alpha[e] = dot(Q[dst], K[src]) * scale; atomicMax per dst
template<int C>
__global__ void edge_alpha(const float* __restrict__ Q, const float* __restrict__ Km,
                           const int* __restrict__ src, const int* __restrict__ dst,
                           float* __restrict__ alpha, unsigned* __restrict__ amaxU,
                           float scale)
{
    int gi = blockIdx.x * blockDim.x + threadIdx.x;
    int e = gi >> 6, lane = threadIdx.x & 63;
    if (e >= NE) return;
    int s = src[e], d = dst[e];
    const float4* q4 = (const float4*)(Q  + (size_t)d * C);
    const float4* k4 = (const float4*)(Km + (size_t)s * C);
    float sum = 0.f;
    #pragma unroll
    for (int i = 0; i < C / 256; ++i) {
        float4 a = q4[lane + 64 * i], b = k4[lane + 64 * i];
        sum += a.x * b.x + a.y * b.y + a.z * b.z + a.w * b.w;
    }
    #pragma unroll
    for (int off = 32; off; off >>= 1) sum += __shfl_down(sum, off);
    if (lane == 0) {
        float al = sum * scale;
        alpha[e] = al;
        atomicMax(&amaxU[d], enc_f(al));
    }
}

__global__ void edge_expsum(const float* __restrict__ alpha, const int* __restrict__ dst,
                            const unsigned* __restrict__ amaxU,
                            float* __restrict__ ev, float* __restrict__ denom)
{
    int e = blockIdx.x * blockDim.x + threadIdx.x;
    if (e >= NE) return;
    int d = dst[e];
    float ex = expf(alpha[e] - dec_f(amaxU[d]));
    ev[e] = ex;
    atomicAdd(&denom[d], ex);
}

// one wave per edge: acc[dst] += (ev/denom)*(1/H) * V[src]
template<int C>
__global__ void edge_aggr(const float* __restrict__ ev, const float* __restrict__ denom,
                          const float* __restrict__ V,
                          const int* __restrict__ src, const int* __restrict__ dst,
                          float* __restrict__ acc, float hinv)
{
    int gi = blockIdx.x * blockDim.x + threadIdx.x;
    int e = gi >> 6, lane = threadIdx.x & 63;
    if (e >= NE) return;
    int s = src[e], d = dst[e];
    float coeff = ev[e] / (denom[d] + 1e-16f) * hinv;
    const float4* v4 = (const float4*)(V + (size_t)s * C);
    float* ap = acc + (size_t)d * C;
    #pragma unroll
    for (int i = 0; i < C / 256; ++i) {
        float4 v = v4[lane + 64 * i];
        int base = (lane + 64 * i) * 4;
        atomicAdd(ap + base + 0, coeff * v.x);
        atomicAdd(ap + base + 1, coeff * v.y);
        atomicAdd(ap + base + 2, coeff * v.z);
        atomicAdd(ap + base + 3, coeff * v.w);
    }
}

__global__ void elu_k(float* __restrict__ x, int n) {
    int i = blockIdx.x * blockDim.x + threadIdx.x;
    if (i < n) { float v = x[i]; x[i] = v > 0.f ? v : expm1f(v); }
}

// one wave per node: glogit[n] = dot(H2[n], Wg) + bg; atomicMax per graph
__global__ void gate_logit(const float* __restrict__ H2, const float* __restrict__ Wg,
                           const float* __restrict__ bg, const int* __restrict__ batch,
                           float* __restrict__ glogit, unsigned* __restrict__ gamax)
{
    int gi = blockIdx.x * blockDim.x + threadIdx.x;
    int n = gi >> 6, lane = threadIdx.x & 63;
    if (n >= NN) return;
    float4 h = ((const float4*)(H2 + (size_t)n * C2))[lane];
    float4 w = ((const float4*)Wg)[lane];
    float sum = h.x * w.x + h.y * w.y + h.z * w.z + h.w * w.w;
    #pragma unroll
    for (int off = 32; off; off >>= 1) sum += __shfl_down(sum, off);
    if (lane == 0) {
        float v = sum + bg[0];
        glogit[n] = v;
        atomicMax(&gamax[batch[n]], enc_f(v));
    }
}

__global__ void gate_expsum(const float* __restrict__ glogit, const int* __restrict__ batch,
                            const unsigned* __restrict__ gamax,
                            float* __restrict__ gev, float* __restrict__ gdenom)
{
    int n = blockIdx.x * blockDim.x + threadIdx.x;
    if (n >= NN) return;
    int b = batch[n];
    float ex = expf(glogit[n] - dec_f(gamax[b]));
    gev[n] = ex;
    atomicAdd(&gdenom[b], ex);
}

__global__ void gate_aggr(const float* __restrict__ gev, const float* __restrict__ gdenom,
                          const float* __restrict__ H2, const int* __restrict__ batch,
                          float* __restrict__ g)
{
    int gi = blockIdx.x * blockDim.x + threadIdx.x;
    int n = gi >> 6, lane = threadIdx.x & 63;
    if (n >= NN) return;
    int b = batch[n];
    float coeff = gev[n] / (gdenom[b] + 1e-16f);
    float4 h = ((const float4*)(H2 + (size_t)n * C2))[lane];
    float* gp = g + (size_t)b * C2 + lane * 4;
    atomicAdd(gp + 0, coeff * h.x);
    atomicAdd(gp + 1, coeff * h.y);
    atomicAdd(gp + 2, coeff * h.z);
    atomicAdd(gp + 3, coeff * h.w);
}

__global__ void final_fc(const float* __restrict__ g, const float* __restrict__ Wf,
                         const float* __restrict__ bf, float* __restrict__ out)
{
    int i = blockIdx.x * blockDim.x + threadIdx.x;
    if (i >= NB * NOUT) return;
    int b = i / NOUT, o = i % NOUT;
    float s = bf[o];
    for (int k = 0; k < C2; ++k) s += g[b * C2 + k] * Wf[k * NOUT + o];
    out[i] = s;
}

extern "C" void kernel_launch(void* const* d_in, const int* in_sizes, int n_in,
                              void* d_out, int out_size, void* d_ws, size_t ws_size,
                              hipStream_t stream) {
    (void)in_sizes; (void)n_in; (void)out_size; (void)ws_size;
    const float* x     = (const float*)d_in[0];
    const int*   ei    = (const int*)  d_in[1];
    const int*   batch = (const int*)  d_in[2];
    const float* Wq1 = (const float*)d_in[3];  const float* bq1 = (const float*)d_in[4];
    const float* Wk1 = (const float*)d_in[5];  const float* bk1 = (const float*)d_in[6];
    const float* Wv1 = (const float*)d_in[7];  const float* bv1 = (const float*)d_in[8];
    const float* Ws1 = (const float*)d_in[9];  const float* bs1 = (const float*)d_in[10];
    const float* Wq2 = (const float*)d_in[11]; const float* bq2 = (const float*)d_in[12];
    const float* Wk2 = (const float*)d_in[13]; const float* bk2 = (const float*)d_in[14];
    const float* Wv2 = (const float*)d_in[15]; const float* bv2 = (const float*)d_in[16];
    const float* Ws2 = (const float*)d_in[17]; const float* bs2 = (const float*)d_in[18];
    const float* Wg  = (const float*)d_in[19]; const float* bg  = (const float*)d_in[20];
    const float* Wf  = (const float*)d_in[21]; const float* bf  = (const float*)d_in[22];

    const int* src = ei;        // edge_index[0]
    const int* dst = ei + NE;   // edge_index[1]

    // workspace layout (floats)
    float* ws = (float*)d_ws;
    size_t o = 0;
    float* bufA  = ws + o; o += (size_t)NN * C1;   // per-head Q
    float* bufB  = ws + o; o += (size_t)NN * C1;   // per-head K, then V
    float* acc1  = ws + o; o += (size_t)NN * C1;   // conv1 out / h1
    float* acc2  = ws + o; o += (size_t)NN * C2;   // conv2 out / h2
    float* alpha = ws + o; o += NE;                // also gate logits (NN<=NE? no: NN=10000<NE=20000 ok)
    float* ev    = ws + o; o += NE;                // also gate exp
    unsigned* amaxU = (unsigned*)(ws + o); o += NN; // also pool amax (NB<=NN)
    float* denom = ws + o; o += NN;                // also pool denom
    float* g     = ws + o; o += (size_t)NB * C2;

    const dim3 blk(256);
    const dim3 gemm_grid1(C1 / 64, (NN + 63) / 64);
    const dim3 gemm_grid2(C2 / 64, (NN + 63) / 64);
    const int edge_blocks = (NE * 64) / 256;      // 5000
    const int node_blocks = (NN * 64) / 256;      // 2500
    const float sc1 = 1.0f / sqrtf((float)C1);
    const float sc2 = 1.0f / sqrtf((float)C2);

    // ---------------- conv1 ----------------
    // skip: acc1 = x @ Ws1 + bs1
    gemm_bias<<<gemm_grid1, blk, 0, stream>>>(x, FIN, Ws1, C1, bs1, acc1, C1, NN, FIN);
    for (int h = 0; h < NHEAD; ++h) {
        gemm_bias<<<gemm_grid1, blk, 0, stream>>>(x, FIN, Wq1 + h * C1, NHEAD * C1,
                                                  bq1 + h * C1, bufA, C1, NN, FIN);
        gemm_bias<<<gemm_grid1, blk, 0, stream>>>(x, FIN, Wk1 + h * C1, NHEAD * C1,
                                                  bk1 + h * C1, bufB, C1, NN, FIN);
        init_seg<<<(NN + 255) / 256, blk, 0, stream>>>(amaxU, denom, NN);
        edge_alpha<C1><<<edge_blocks, blk, 0, stream>>>(bufA, bufB, src, dst, alpha, amaxU, sc1);
        edge_expsum<<<(NE + 255) / 256, blk, 0, stream>>>(alpha, dst, amaxU, ev, denom);
        gemm_bias<<<gemm_grid1, blk, 0, stream>>>(x, FIN, Wv1 + h * C1, NHEAD * C1,
                                                  bv1 + h * C1, bufB, C1, NN, FIN);
        edge_aggr<C1><<<edge_blocks, blk, 0, stream>>>(ev, denom, bufB, src, dst, acc1,
                                                       1.0f / NHEAD);
    }
    elu_k<<<((size_t)NN * C1 + 255) / 256, blk, 0, stream>>>(acc1, NN * C1);

    // ---------------- conv2 ----------------
    gemm_bias<<<gemm_grid2, blk, 0, stream>>>(acc1, C1, Ws2, C2, bs2, acc2, C2, NN, C1);
    for (int h = 0; h < NHEAD; ++h) {
        gemm_bias<<<gemm_grid2, blk, 0, stream>>>(acc1, C1, Wq2 + h * C2, NHEAD * C2,
                                                  bq2 + h * C2, bufA, C2, NN, C1);
        gemm_bias<<<gemm_grid2, blk, 0, stream>>>(acc1, C1, Wk2 + h * C2, NHEAD * C2,
                                                  bk2 + h * C2, bufB, C2, NN, C1);
        init_seg<<<(NN + 255) / 256, blk, 0, stream>>>(amaxU, denom, NN);
        edge_alpha<C2><<<edge_blocks, blk, 0, stream>>>(bufA, bufB, src, dst, alpha, amaxU, sc2);
        edge_expsum<<<(NE + 255) / 256, blk, 0, stream>>>(alpha, dst, amaxU, ev, denom);
        gemm_bias<<<gemm_grid2, blk, 0, stream>>>(acc1, C1, Wv2 + h * C2, NHEAD * C2,
                                                  bv2 + h * C2, bufB, C2, NN, C1);
        edge_aggr<C2><<<edge_blocks, blk, 0, stream>>>(ev, denom, bufB, src, dst, acc2,
                                                       1.0f / NHEAD);
    }
    elu_k<<<((size_t)NN * C2 + 255) / 256, blk, 0, stream>>>(acc2, NN * C2);

    // ---------------- global attention pooling + fc ----------------
    init_pool<<<(NB * C2 + 255) / 256, blk, 0, stream>>>(amaxU, denom, g);
    gate_logit<<<node_blocks, blk, 0, stream>>>(acc2, Wg, bg, batch, alpha, amaxU);
    gate_expsum<<<(NN + 255) / 256, blk, 0, stream>>>(alpha, batch, amaxU, ev, denom);
    gate_aggr<<<node_blocks, blk, 0, stream>>>(ev, denom, acc2, batch, g);
    final_fc<<<(NB * NOUT + 255) / 256, blk, 0, stream>>>(g, Wf, bf, (float*)d_out);
}

// Round 5
// 888.679 us; speedup vs baseline: 4.5541x; 4.5541x over previous
//
#include <hip/hip_runtime.h>
#include <math.h>

#define NN 10000
#define NE 20000
#define FIN 128
#define NHEAD 8
#define C1 512
#define C2 256
#define NB 64
#define NOUT 10

typedef _Float16 half8v __attribute__((ext_vector_type(8)));
typedef _Float16 half4v __attribute__((ext_vector_type(4)));
typedef float f32x4 __attribute__((ext_vector_type(4)));

template<int VEC> struct VecT;
template<> struct VecT<4> { using T = half4v; };
template<> struct VecT<8> { using T = half8v; };

// monotone float<->uint encoding for atomic max on floats
__device__ __forceinline__ unsigned enc_f(float f) {
    unsigned u = __float_as_uint(f);
    return (u & 0x80000000u) ? ~u : (u | 0x80000000u);
}
__device__ __forceinline__ float dec_f(unsigned e) {
    return (e & 0x80000000u) ? __uint_as_float(e & 0x7fffffffu) : __uint_as_float(~e);
}

// ---------------- conversion / transpose ----------------
__global__ void cvt_f16(const float* __restrict__ in, _Float16* __restrict__ out, int n) {
    int i = blockIdx.x * blockDim.x + threadIdx.x;
    if (i < n) out[i] = (_Float16)in[i];
}

// W [K,N] fp32 -> Wt [N,K] f16.  K,N multiples of 32. block (32,8)
__global__ void transpose_cvt(const float* __restrict__ W, _Float16* __restrict__ Wt,
                              int K, int N) {
    __shared__ float tile[32][33];
    int n0 = blockIdx.x * 32, k0 = blockIdx.y * 32;
    int tx = threadIdx.x, ty = threadIdx.y;
    for (int j = ty; j < 32; j += 8) tile[j][tx] = W[(size_t)(k0 + j) * N + n0 + tx];
    __syncthreads();
    for (int j = ty; j < 32; j += 8)
        Wt[(size_t)(n0 + j) * K + k0 + tx] = (_Float16)tile[tx][j];
}

// ---------------- MFMA GEMM:  C[M,Ncols] = A[M,K] @ Bt[Ncols,K]^T + bias ----------------
// A row-major f16, Bt row-major f16 (rows are output columns). Ncols % 128 == 0, K % 32 == 0.
template<bool OUT_HALF>
__global__ __launch_bounds__(256) void gemm_tn(
    const _Float16* __restrict__ A, const _Float16* __restrict__ Bt,
    const float* __restrict__ bias, void* __restrict__ Cout, int ldc,
    int M, int K)
{
    __shared__ _Float16 As[128][40];   // 80B row stride (16B-aligned)
    __shared__ _Float16 Bs[128][40];
    const int t = threadIdx.x;
    const int m0 = blockIdx.y * 128, n0 = blockIdx.x * 128;
    const int w = t >> 6, lane = t & 63;
    const int wr = w >> 1, wc = w & 1;

    f32x4 acc[4][4];
    #pragma unroll
    for (int m = 0; m < 4; ++m)
        #pragma unroll
        for (int n = 0; n < 4; ++n)
            #pragma unroll
            for (int j = 0; j < 4; ++j) acc[m][n][j] = 0.f;

    for (int k0 = 0; k0 < K; k0 += 32) {
        #pragma unroll
        for (int i = 0; i < 2; ++i) {
            int c = t + i * 256;
            int row = c >> 2, kc = c & 3;
            int gr = m0 + row; gr = gr < M ? gr : M - 1;
            float4 va = *(const float4*)(A + (size_t)gr * K + k0 + kc * 8);
            *(float4*)(&As[row][kc * 8]) = va;
            float4 vb = *(const float4*)(Bt + (size_t)(n0 + row) * K + k0 + kc * 8);
            *(float4*)(&Bs[row][kc * 8]) = vb;
        }
        __syncthreads();
        half8v af[4], bf[4];
        #pragma unroll
        for (int m = 0; m < 4; ++m)
            af[m] = *(const half8v*)(&As[wr * 64 + m * 16 + (lane & 15)][(lane >> 4) * 8]);
        #pragma unroll
        for (int n = 0; n < 4; ++n)
            bf[n] = *(const half8v*)(&Bs[wc * 64 + n * 16 + (lane & 15)][(lane >> 4) * 8]);
        #pragma unroll
        for (int m = 0; m < 4; ++m)
            #pragma unroll
            for (int n = 0; n < 4; ++n)
                acc[m][n] = __builtin_amdgcn_mfma_f32_16x16x32_f16(af[m], bf[n], acc[m][n], 0, 0, 0);
        __syncthreads();
    }
    #pragma unroll
    for (int m = 0; m < 4; ++m) {
        int r0 = m0 + wr * 64 + m * 16 + (lane >> 4) * 4;
        #pragma unroll
        for (int n = 0; n < 4; ++n) {
            int col = n0 + wc * 64 + n * 16 + (lane & 15);
            float b = bias[col];
            #pragma unroll
            for (int r = 0; r < 4; ++r) {
                int row = r0 + r;
                if (row < M) {
                    float v = acc[m][n][r] + b;
                    if (OUT_HALF) ((_Float16*)Cout)[(size_t)row * ldc + col] = (_Float16)v;
                    else          ((float*)Cout)[(size_t)row * ldc + col] = v;
                }
            }
        }
    }
}

// ---------------- CSR build (by dst) ----------------
__global__ void zero_i32(int* __restrict__ p, int n) {
    int i = blockIdx.x * blockDim.x + threadIdx.x;
    if (i < n) p[i] = 0;
}
__global__ void hist_dst(const int* __restrict__ dst, int* __restrict__ deg) {
    int e = blockIdx.x * blockDim.x + threadIdx.x;
    if (e < NE) atomicAdd(&deg[dst[e]], 1);
}
// single-block exclusive scan over deg[0..n) -> rowptr, cursor; rowptr[n]=total
__global__ void scan_deg(const int* __restrict__ deg, int* __restrict__ rowptr,
                         int* __restrict__ cursor, int n) {
    __shared__ int s[256];
    __shared__ int carry;
    int t = threadIdx.x;
    if (t == 0) carry = 0;
    __syncthreads();
    for (int base = 0; base < n; base += 256) {
        int v = (base + t < n) ? deg[base + t] : 0;
        s[t] = v;
        __syncthreads();
        for (int off = 1; off < 256; off <<= 1) {
            int x = (t >= off) ? s[t - off] : 0;
            __syncthreads();
            s[t] += x;
            __syncthreads();
        }
        int excl = carry + s[t] - v;
        if (base + t < n) { rowptr[base + t] = excl; cursor[base + t] = excl; }
        __syncthreads();
        if (t == 255) carry += s[255];
        __syncthreads();
    }
    if (t == 0) rowptr[n] = carry;
}
__global__ void scatter_edges(const int* __restrict__ dst, int* __restrict__ cursor,
                              int* __restrict__ eids) {
    int e = blockIdx.x * blockDim.x + threadIdx.x;
    if (e < NE) {
        int pos = atomicAdd(&cursor[dst[e]], 1);
        eids[pos] = e;
    }
}

// ---------------- segment softmax pieces ----------------
__global__ void init_seg(unsigned* __restrict__ amax, float* __restrict__ denom, int n) {
    int i = blockIdx.x * blockDim.x + threadIdx.x;
    if (i < n) { amax[i] = 0x007FFFFFu; denom[i] = 0.f; }  // enc(-inf)
}

// one wave per edge, G heads fused: alpha[e,h]=dot(Q[dst,h],K[src,h])*scale
template<int C>
__global__ void edge_alpha_f(const _Float16* __restrict__ Q, const _Float16* __restrict__ Kh,
                             const int* __restrict__ src, const int* __restrict__ dst,
                             float* __restrict__ alpha, unsigned* __restrict__ amaxU,
                             float scale, int hbase, int G)
{
    constexpr int VEC = C / 64;
    using vecH = typename VecT<VEC>::T;
    int gi = blockIdx.x * blockDim.x + threadIdx.x;
    int e = gi >> 6, lane = threadIdx.x & 63;
    if (e >= NE) return;
    int s = src[e], d = dst[e];
    const _Float16* qp = Q + (size_t)d * ((size_t)G * C) + lane * VEC;
    const _Float16* kp = Kh + (size_t)s * ((size_t)G * C) + lane * VEC;
    for (int h = 0; h < G; ++h) {
        vecH q = *(const vecH*)(qp + h * C);
        vecH k = *(const vecH*)(kp + h * C);
        float sum = 0.f;
        #pragma unroll
        for (int j = 0; j < VEC; ++j) sum += (float)q[j] * (float)k[j];
        #pragma unroll
        for (int off = 32; off; off >>= 1) sum += __shfl_xor(sum, off);
        if (lane == 0) {
            float al = sum * scale;
            alpha[(size_t)e * NHEAD + hbase + h] = al;
            atomicMax(&amaxU[(size_t)d * NHEAD + hbase + h], enc_f(al));
        }
    }
}

// all (e,h): ev = exp(alpha - amax[dst,h]); denom[dst,h] += ev
__global__ void edge_expsum(const float* __restrict__ alpha, const int* __restrict__ dst,
                            const unsigned* __restrict__ amaxU,
                            float* __restrict__ ev, float* __restrict__ denom)
{
    int i = blockIdx.x * blockDim.x + threadIdx.x;
    if (i >= NE * NHEAD) return;
    int e = i >> 3, h = i & 7;
    int d = dst[e];
    float ex = expf(alpha[i] - dec_f(amaxU[(size_t)d * NHEAD + h]));
    ev[i] = ex;
    atomicAdd(&denom[(size_t)d * NHEAD + h], ex);
}

// one wave per node, CSR gather, G heads fused, no atomics:
// acc[n] += sum_h (1/H) * sum_{e in in(n)} (ev/denom) * V[src(e), h]
template<int C>
__global__ void node_aggr(const _Float16* __restrict__ V, const float* __restrict__ ev,
                          const float* __restrict__ denom, const int* __restrict__ rowptr,
                          const int* __restrict__ eids, const int* __restrict__ src,
                          float* __restrict__ acc, int hbase, int G)
{
    constexpr int VEC = C / 64;
    using vecH = typename VecT<VEC>::T;
    int gi = blockIdx.x * blockDim.x + threadIdx.x;
    int n = gi >> 6, lane = threadIdx.x & 63;
    if (n >= NN) return;
    int beg = rowptr[n], end = rowptr[n + 1];
    float a[VEC];
    #pragma unroll
    for (int j = 0; j < VEC; ++j) a[j] = 0.f;
    for (int h = 0; h < G; ++h) {
        float rd = 1.f / (denom[(size_t)n * NHEAD + hbase + h] + 1e-16f) * (1.f / NHEAD);
        for (int i = beg; i < end; ++i) {
            int e = eids[i];
            int s = src[e];
            float coeff = ev[(size_t)e * NHEAD + hbase + h] * rd;
            vecH v = *(const vecH*)(V + (size_t)s * ((size_t)G * C) + h * C + lane * VEC);
            #pragma unroll
            for (int j = 0; j < VEC; ++j) a[j] += coeff * (float)v[j];
        }
    }
    float* ap = acc + (size_t)n * C + lane * VEC;
    #pragma unroll
    for (int j = 0; j < VEC; ++j) ap[j] += a[j];
}

__global__ void elu_k(float* __restrict__ x, int n) {
    int i = blockIdx.x * blockDim.x + threadIdx.x;
    if (i < n) { float v = x[i]; x[i] = v > 0.f ? v : expm1f(v); }
}
__global__ void elu_cvt(const float* __restrict__ in, _Float16* __restrict__ out, int n) {
    int i = blockIdx.x * blockDim.x + threadIdx.x;
    if (i < n) { float v = in[i]; v = v > 0.f ? v : expm1f(v); out[i] = (_Float16)v; }
}

// ---------------- global-attention pooling + fc ----------------
__global__ void init_pool(unsigned* __restrict__ amax, float* __restrict__ denom,
                          float* __restrict__ g) {
    int i = blockIdx.x * blockDim.x + threadIdx.x;
    if (i < NB) { amax[i] = 0x007FFFFFu; denom[i] = 0.f; }
    if (i < NB * C2) g[i] = 0.f;
}
__global__ void gate_logit(const float* __restrict__ H2, const float* __restrict__ Wg,
                           const float* __restrict__ bg, const int* __restrict__ batch,
                           float* __restrict__ glogit, unsigned* __restrict__ gamax)
{
    int gi = blockIdx.x * blockDim.x + threadIdx.x;
    int n = gi >> 6, lane = threadIdx.x & 63;
    if (n >= NN) return;
    float4 h = ((const float4*)(H2 + (size_t)n * C2))[lane];
    float4 w = ((const float4*)Wg)[lane];
    float sum = h.x * w.x + h.y * w.y + h.z * w.z + h.w * w.w;
    #pragma unroll
    for (int off = 32; off; off >>= 1) sum += __shfl_down(sum, off);
    if (lane == 0) {
        float v = sum + bg[0];
        glogit[n] = v;
        atomicMax(&gamax[batch[n]], enc_f(v));
    }
}
__global__ void gate_expsum(const float* __restrict__ glogit, const int* __restrict__ batch,
                            const unsigned* __restrict__ gamax,
                            float* __restrict__ gev, float* __restrict__ gdenom)
{
    int n = blockIdx.x * blockDim.x + threadIdx.x;
    if (n >= NN) return;
    int b = batch[n];
    float ex = expf(glogit[n] - dec_f(gamax[b]));
    gev[n] = ex;
    atomicAdd(&gdenom[b], ex);
}
__global__ void gate_aggr(const float* __restrict__ gev, const float* __restrict__ gdenom,
                          const float* __restrict__ H2, const int* __restrict__ batch,
                          float* __restrict__ g)
{
    int gi = blockIdx.x * blockDim.x + threadIdx.x;
    int n = gi >> 6, lane = threadIdx.x & 63;
    if (n >= NN) return;
    int b = batch[n];
    float coeff = gev[n] / (gdenom[b] + 1e-16f);
    float4 h = ((const float4*)(H2 + (size_t)n * C2))[lane];
    float* gp = g + (size_t)b * C2 + lane * 4;
    atomicAdd(gp + 0, coeff * h.x);
    atomicAdd(gp + 1, coeff * h.y);
    atomicAdd(gp + 2, coeff * h.z);
    atomicAdd(gp + 3, coeff * h.w);
}
__global__ void final_fc(const float* __restrict__ g, const float* __restrict__ Wf,
                         const float* __restrict__ bf, float* __restrict__ out)
{
    int i = blockIdx.x * blockDim.x + threadIdx.x;
    if (i >= NB * NOUT) return;
    int b = i / NOUT, o = i % NOUT;
    float s = bf[o];
    for (int k = 0; k < C2; ++k) s += g[b * C2 + k] * Wf[k * NOUT + o];
    out[i] = s;
}

extern "C" void kernel_launch(void* const* d_in, const int* in_sizes, int n_in,
                              void* d_out, int out_size, void* d_ws, size_t ws_size,
                              hipStream_t stream) {
    (void)in_sizes; (void)n_in; (void)out_size;
    const float* x     = (const float*)d_in[0];
    const int*   ei    = (const int*)  d_in[1];
    const int*   batch = (const int*)  d_in[2];
    const float* Wq1 = (const float*)d_in[3];  const float* bq1 = (const float*)d_in[4];
    const float* Wk1 = (const float*)d_in[5];  const float* bk1 = (const float*)d_in[6];
    const float* Wv1 = (const float*)d_in[7];  const float* bv1 = (const float*)d_in[8];
    const float* Ws1 = (const float*)d_in[9];  const float* bs1 = (const float*)d_in[10];
    const float* Wq2 = (const float*)d_in[11]; const float* bq2 = (const float*)d_in[12];
    const float* Wk2 = (const float*)d_in[13]; const float* bk2 = (const float*)d_in[14];
    const float* Wv2 = (const float*)d_in[15]; const float* bv2 = (const float*)d_in[16];
    const float* Ws2 = (const float*)d_in[17]; const float* bs2 = (const float*)d_in[18];
    const float* Wg  = (const float*)d_in[19]; const float* bg  = (const float*)d_in[20];
    const float* Wf  = (const float*)d_in[21]; const float* bf  = (const float*)d_in[22];

    const int* src = ei;
    const int* dst = ei + NE;

    // ---- workspace layout (256B-aligned chunks); group buffers last ----
    char* base = (char*)d_ws;
    size_t off = 0;
    auto alloc = [&](size_t bytes) -> char* {
        char* p = base + off;
        off = (off + bytes + 255) & ~(size_t)255;
        return p;
    };
    _Float16* xb   = (_Float16*)alloc((size_t)NN * FIN * 2);
    _Float16* wtq1 = (_Float16*)alloc((size_t)NHEAD * C1 * FIN * 2);
    _Float16* wtk1 = (_Float16*)alloc((size_t)NHEAD * C1 * FIN * 2);
    _Float16* wtv1 = (_Float16*)alloc((size_t)NHEAD * C1 * FIN * 2);
    _Float16* wts1 = (_Float16*)alloc((size_t)C1 * FIN * 2);
    _Float16* wtq2 = (_Float16*)alloc((size_t)NHEAD * C2 * C1 * 2);
    _Float16* wtk2 = (_Float16*)alloc((size_t)NHEAD * C2 * C1 * 2);
    _Float16* wtv2 = (_Float16*)alloc((size_t)NHEAD * C2 * C1 * 2);
    _Float16* wts2 = (_Float16*)alloc((size_t)C2 * C1 * 2);
    float* acc1 = (float*)alloc((size_t)NN * C1 * 4);   // conv1 accum; acc2 aliases front half
    _Float16* h1b = (_Float16*)alloc((size_t)NN * C1 * 2);
    float* alpha = (float*)alloc((size_t)NE * NHEAD * 4);
    float* ev    = (float*)alloc((size_t)NE * NHEAD * 4);
    unsigned* amaxU = (unsigned*)alloc((size_t)NN * NHEAD * 4);
    float* denom = (float*)alloc((size_t)NN * NHEAD * 4);
    int* deg    = (int*)alloc((size_t)NN * 4);
    int* rowptr = (int*)alloc((size_t)(NN + 1) * 4);
    int* cursor = (int*)alloc((size_t)NN * 4);
    int* eids   = (int*)alloc((size_t)NE * 4);
    float* g    = (float*)alloc((size_t)NB * C2 * 4);
    size_t fixed_end = off;
    float* acc2 = acc1;  // alias: conv1 result dead once h1b is built

    // pick largest head-group G whose Q/K buffers fit ws_size
    int G = 1;
    for (int cand = 8; cand >= 1; cand >>= 1) {
        size_t qk = (((size_t)NN * cand * C1 * 2) + 255) & ~(size_t)255;
        if (fixed_end + 2 * qk <= ws_size) { G = cand; break; }
        if (cand == 1) G = 1;  // guaranteed by round-1's 72MB success
    }
    size_t qk_bytes = (((size_t)NN * G * C1 * 2) + 255) & ~(size_t)255;
    _Float16* Qbuf = (_Float16*)(base + fixed_end);
    _Float16* Kbuf = (_Float16*)(base + fixed_end + qk_bytes);
    _Float16* Vbuf = Qbuf;  // V reuses Q after alpha pass

    const dim3 blk(256);
    const float sc1 = 1.0f / sqrtf((float)C1);
    const float sc2 = 1.0f / sqrtf((float)C2);
    const int edge_blocks = (NE * 64) / 256;
    const int node_blocks = (NN * 64) / 256;
    const int gy = (NN + 127) / 128;   // 79

    // ---- conversions ----
    cvt_f16<<<((size_t)NN * FIN + 255) / 256, blk, 0, stream>>>(x, xb, NN * FIN);
    {
        dim3 tb(32, 8);
        transpose_cvt<<<dim3(NHEAD * C1 / 32, FIN / 32), tb, 0, stream>>>(Wq1, wtq1, FIN, NHEAD * C1);
        transpose_cvt<<<dim3(NHEAD * C1 / 32, FIN / 32), tb, 0, stream>>>(Wk1, wtk1, FIN, NHEAD * C1);
        transpose_cvt<<<dim3(NHEAD * C1 / 32, FIN / 32), tb, 0, stream>>>(Wv1, wtv1, FIN, NHEAD * C1);
        transpose_cvt<<<dim3(C1 / 32, FIN / 32),         tb, 0, stream>>>(Ws1, wts1, FIN, C1);
        transpose_cvt<<<dim3(NHEAD * C2 / 32, C1 / 32),  tb, 0, stream>>>(Wq2, wtq2, C1, NHEAD * C2);
        transpose_cvt<<<dim3(NHEAD * C2 / 32, C1 / 32),  tb, 0, stream>>>(Wk2, wtk2, C1, NHEAD * C2);
        transpose_cvt<<<dim3(NHEAD * C2 / 32, C1 / 32),  tb, 0, stream>>>(Wv2, wtv2, C1, NHEAD * C2);
        transpose_cvt<<<dim3(C2 / 32, C1 / 32),          tb, 0, stream>>>(Ws2, wts2, C1, C2);
    }

    // ---- CSR by dst ----
    zero_i32<<<(NN + 255) / 256, blk, 0, stream>>>(deg, NN);
    hist_dst<<<(NE + 255) / 256, blk, 0, stream>>>(dst, deg);
    scan_deg<<<1, blk, 0, stream>>>(deg, rowptr, cursor, NN);
    scatter_edges<<<(NE + 255) / 256, blk, 0, stream>>>(dst, cursor, eids);

    // ================ conv1 ================
    gemm_tn<false><<<dim3(C1 / 128, gy), blk, 0, stream>>>(xb, wts1, bs1, acc1, C1, NN, FIN);
    init_seg<<<(NN * NHEAD + 255) / 256, blk, 0, stream>>>(amaxU, denom, NN * NHEAD);
    for (int hb = 0; hb < NHEAD; hb += G) {
        gemm_tn<true><<<dim3(G * C1 / 128, gy), blk, 0, stream>>>(
            xb, wtq1 + (size_t)hb * C1 * FIN, bq1 + hb * C1, Qbuf, G * C1, NN, FIN);
        gemm_tn<true><<<dim3(G * C1 / 128, gy), blk, 0, stream>>>(
            xb, wtk1 + (size_t)hb * C1 * FIN, bk1 + hb * C1, Kbuf, G * C1, NN, FIN);
        edge_alpha_f<C1><<<edge_blocks, blk, 0, stream>>>(Qbuf, Kbuf, src, dst, alpha, amaxU,
                                                          sc1, hb, G);
    }
    edge_expsum<<<(NE * NHEAD + 255) / 256, blk, 0, stream>>>(alpha, dst, amaxU, ev, denom);
    for (int hb = 0; hb < NHEAD; hb += G) {
        gemm_tn<true><<<dim3(G * C1 / 128, gy), blk, 0, stream>>>(
            xb, wtv1 + (size_t)hb * C1 * FIN, bv1 + hb * C1, Vbuf, G * C1, NN, FIN);
        node_aggr<C1><<<node_blocks, blk, 0, stream>>>(Vbuf, ev, denom, rowptr, eids, src,
                                                       acc1, hb, G);
    }
    elu_cvt<<<((size_t)NN * C1 + 255) / 256, blk, 0, stream>>>(acc1, h1b, NN * C1);

    // ================ conv2 ================
    gemm_tn<false><<<dim3(C2 / 128, gy), blk, 0, stream>>>(h1b, wts2, bs2, acc2, C2, NN, C1);
    init_seg<<<(NN * NHEAD + 255) / 256, blk, 0, stream>>>(amaxU, denom, NN * NHEAD);
    for (int hb = 0; hb < NHEAD; hb += G) {
        gemm_tn<true><<<dim3(G * C2 / 128, gy), blk, 0, stream>>>(
            h1b, wtq2 + (size_t)hb * C2 * C1, bq2 + hb * C2, Qbuf, G * C2, NN, C1);
        gemm_tn<true><<<dim3(G * C2 / 128, gy), blk, 0, stream>>>(
            h1b, wtk2 + (size_t)hb * C2 * C1, bk2 + hb * C2, Kbuf, G * C2, NN, C1);
        edge_alpha_f<C2><<<edge_blocks, blk, 0, stream>>>(Qbuf, Kbuf, src, dst, alpha, amaxU,
                                                          sc2, hb, G);
    }
    edge_expsum<<<(NE * NHEAD + 255) / 256, blk, 0, stream>>>(alpha, dst, amaxU, ev, denom);
    for (int hb = 0; hb < NHEAD; hb += G) {
        gemm_tn<true><<<dim3(G * C2 / 128, gy), blk, 0, stream>>>(
            h1b, wtv2 + (size_t)hb * C2 * C1, bv2 + hb * C2, Vbuf, G * C2, NN, C1);
        node_aggr<C2><<<node_blocks, blk, 0, stream>>>(Vbuf, ev, denom, rowptr, eids, src,
                                                       acc2, hb, G);
    }
    elu_k<<<((size_t)NN * C2 + 255) / 256, blk, 0, stream>>>(acc2, NN * C2);

    // ================ pooling + fc ================
    init_pool<<<(NB * C2 + 255) / 256, blk, 0, stream>>>(amaxU, denom, g);
    gate_logit<<<node_blocks, blk, 0, stream>>>(acc2, Wg, bg, batch, alpha, amaxU);
    gate_expsum<<<(NN + 255) / 256, blk, 0, stream>>>(alpha, batch, amaxU, ev, denom);
    gate_aggr<<<node_blocks, blk, 0, stream>>>(ev, denom, acc2, batch, g);
    final_fc<<<(NB * NOUT + 255) / 256, blk, 0, stream>>>(g, Wf, bf, (float*)d_out);
}

// Round 6
// 741.616 us; speedup vs baseline: 5.4572x; 1.1983x over previous
//
#include <hip/hip_runtime.h>
#include <math.h>

#define NN 10000
#define NE 20000
#define FIN 128
#define NHEAD 8
#define C1 512
#define C2 256
#define NB 64
#define NOUT 10

typedef _Float16 half8v __attribute__((ext_vector_type(8)));
typedef _Float16 half4v __attribute__((ext_vector_type(4)));
typedef float f32x4 __attribute__((ext_vector_type(4)));

template<int VEC> struct VecT;
template<> struct VecT<4> { using T = half4v; };
template<> struct VecT<8> { using T = half8v; };

// monotone float<->uint encoding for atomic max on floats
__device__ __forceinline__ unsigned enc_f(float f) {
    unsigned u = __float_as_uint(f);
    return (u & 0x80000000u) ? ~u : (u | 0x80000000u);
}
__device__ __forceinline__ float dec_f(unsigned e) {
    return (e & 0x80000000u) ? __uint_as_float(e & 0x7fffffffu) : __uint_as_float(~e);
}

// ---------------- conversion / transpose ----------------
__global__ void cvt_f16(const float* __restrict__ in, _Float16* __restrict__ out, int n) {
    int i = blockIdx.x * blockDim.x + threadIdx.x;
    if (i < n) out[i] = (_Float16)in[i];
}

// W [K,N] fp32 -> Wt [N,K] f16.  K,N multiples of 32. block (32,8)
__global__ void transpose_cvt(const float* __restrict__ W, _Float16* __restrict__ Wt,
                              int K, int N) {
    __shared__ float tile[32][33];
    int n0 = blockIdx.x * 32, k0 = blockIdx.y * 32;
    int tx = threadIdx.x, ty = threadIdx.y;
    for (int j = ty; j < 32; j += 8) tile[j][tx] = W[(size_t)(k0 + j) * N + n0 + tx];
    __syncthreads();
    for (int j = ty; j < 32; j += 8)
        Wt[(size_t)(n0 + j) * K + k0 + tx] = (_Float16)tile[tx][j];
}

// ---------------- MFMA GEMM:  C[M,Ncols] = A[M,K] @ Bt[Ncols,K]^T + bias ----------------
template<bool OUT_HALF>
__global__ __launch_bounds__(256) void gemm_tn(
    const _Float16* __restrict__ A, const _Float16* __restrict__ Bt,
    const float* __restrict__ bias, void* __restrict__ Cout, int ldc,
    int M, int K)
{
    __shared__ _Float16 As[128][40];   // 80B row stride (16B-aligned, ~2-way banks)
    __shared__ _Float16 Bs[128][40];
    const int t = threadIdx.x;
    const int m0 = blockIdx.y * 128, n0 = blockIdx.x * 128;
    const int w = t >> 6, lane = t & 63;
    const int wr = w >> 1, wc = w & 1;

    f32x4 acc[4][4];
    #pragma unroll
    for (int m = 0; m < 4; ++m)
        #pragma unroll
        for (int n = 0; n < 4; ++n)
            #pragma unroll
            for (int j = 0; j < 4; ++j) acc[m][n][j] = 0.f;

    for (int k0 = 0; k0 < K; k0 += 32) {
        #pragma unroll
        for (int i = 0; i < 2; ++i) {
            int c = t + i * 256;
            int row = c >> 2, kc = c & 3;
            int gr = m0 + row; gr = gr < M ? gr : M - 1;
            float4 va = *(const float4*)(A + (size_t)gr * K + k0 + kc * 8);
            *(float4*)(&As[row][kc * 8]) = va;
            float4 vb = *(const float4*)(Bt + (size_t)(n0 + row) * K + k0 + kc * 8);
            *(float4*)(&Bs[row][kc * 8]) = vb;
        }
        __syncthreads();
        half8v af[4], bf[4];
        #pragma unroll
        for (int m = 0; m < 4; ++m)
            af[m] = *(const half8v*)(&As[wr * 64 + m * 16 + (lane & 15)][(lane >> 4) * 8]);
        #pragma unroll
        for (int n = 0; n < 4; ++n)
            bf[n] = *(const half8v*)(&Bs[wc * 64 + n * 16 + (lane & 15)][(lane >> 4) * 8]);
        #pragma unroll
        for (int m = 0; m < 4; ++m)
            #pragma unroll
            for (int n = 0; n < 4; ++n)
                acc[m][n] = __builtin_amdgcn_mfma_f32_16x16x32_f16(af[m], bf[n], acc[m][n], 0, 0, 0);
        __syncthreads();
    }
    #pragma unroll
    for (int m = 0; m < 4; ++m) {
        int r0 = m0 + wr * 64 + m * 16 + (lane >> 4) * 4;
        #pragma unroll
        for (int n = 0; n < 4; ++n) {
            int col = n0 + wc * 64 + n * 16 + (lane & 15);
            float b = bias[col];
            #pragma unroll
            for (int r = 0; r < 4; ++r) {
                int row = r0 + r;
                if (row < M) {
                    float v = acc[m][n][r] + b;
                    if (OUT_HALF) ((_Float16*)Cout)[(size_t)row * ldc + col] = (_Float16)v;
                    else          ((float*)Cout)[(size_t)row * ldc + col] = v;
                }
            }
        }
    }
}

// ---------------- CSR build (by dst) ----------------
__global__ void zero_i32(int* __restrict__ p, int n) {
    int i = blockIdx.x * blockDim.x + threadIdx.x;
    if (i < n) p[i] = 0;
}
__global__ void hist_dst(const int* __restrict__ dst, int* __restrict__ deg) {
    int e = blockIdx.x * blockDim.x + threadIdx.x;
    if (e < NE) atomicAdd(&deg[dst[e]], 1);
}
__global__ void scan_deg(const int* __restrict__ deg, int* __restrict__ rowptr,
                         int* __restrict__ cursor, int n) {
    __shared__ int s[256];
    __shared__ int carry;
    int t = threadIdx.x;
    if (t == 0) carry = 0;
    __syncthreads();
    for (int base = 0; base < n; base += 256) {
        int v = (base + t < n) ? deg[base + t] : 0;
        s[t] = v;
        __syncthreads();
        for (int off = 1; off < 256; off <<= 1) {
            int x = (t >= off) ? s[t - off] : 0;
            __syncthreads();
            s[t] += x;
            __syncthreads();
        }
        int excl = carry + s[t] - v;
        if (base + t < n) { rowptr[base + t] = excl; cursor[base + t] = excl; }
        __syncthreads();
        if (t == 255) carry += s[255];
        __syncthreads();
    }
    if (t == 0) rowptr[n] = carry;
}
__global__ void scatter_edges(const int* __restrict__ dst, int* __restrict__ cursor,
                              int* __restrict__ eids) {
    int e = blockIdx.x * blockDim.x + threadIdx.x;
    if (e < NE) {
        int pos = atomicAdd(&cursor[dst[e]], 1);
        eids[pos] = e;
    }
}

// ---------------- segment softmax pieces ----------------
__global__ void init_seg(unsigned* __restrict__ amax, float* __restrict__ denom, int n) {
    int i = blockIdx.x * blockDim.x + threadIdx.x;
    if (i < n) { amax[i] = 0x007FFFFFu; denom[i] = 0.f; }  // enc(-inf)
}

// one wave per edge, G heads fused: alpha[e,h]=dot(Q[dst,h],K[src,h])*scale
template<int C>
__global__ void edge_alpha_f(const _Float16* __restrict__ Q, const _Float16* __restrict__ Kh,
                             const int* __restrict__ src, const int* __restrict__ dst,
                             float* __restrict__ alpha, unsigned* __restrict__ amaxU,
                             float scale, int hbase, int G)
{
    constexpr int VEC = C / 64;
    using vecH = typename VecT<VEC>::T;
    int gi = blockIdx.x * blockDim.x + threadIdx.x;
    int e = gi >> 6, lane = threadIdx.x & 63;
    if (e >= NE) return;
    int s = src[e], d = dst[e];
    const _Float16* qp = Q + (size_t)d * ((size_t)G * C) + lane * VEC;
    const _Float16* kp = Kh + (size_t)s * ((size_t)G * C) + lane * VEC;
    for (int h = 0; h < G; ++h) {
        vecH q = *(const vecH*)(qp + h * C);
        vecH k = *(const vecH*)(kp + h * C);
        float sum = 0.f;
        #pragma unroll
        for (int j = 0; j < VEC; ++j) sum += (float)q[j] * (float)k[j];
        #pragma unroll
        for (int off = 32; off; off >>= 1) sum += __shfl_xor(sum, off);
        if (lane == 0) {
            float al = sum * scale;
            alpha[(size_t)e * NHEAD + hbase + h] = al;
            atomicMax(&amaxU[(size_t)d * NHEAD + hbase + h], enc_f(al));
        }
    }
}

// all (e,h): ev = exp(alpha - amax[dst,h]); denom[dst,h] += ev  (contention ~avg-degree=2)
__global__ void edge_expsum(const float* __restrict__ alpha, const int* __restrict__ dst,
                            const unsigned* __restrict__ amaxU,
                            float* __restrict__ ev, float* __restrict__ denom)
{
    int i = blockIdx.x * blockDim.x + threadIdx.x;
    if (i >= NE * NHEAD) return;
    int e = i >> 3, h = i & 7;
    int d = dst[e];
    float ex = expf(alpha[i] - dec_f(amaxU[(size_t)d * NHEAD + h]));
    ev[i] = ex;
    atomicAdd(&denom[(size_t)d * NHEAD + h], ex);
}

// one wave per node, CSR gather, G heads fused, no atomics
template<int C>
__global__ void node_aggr(const _Float16* __restrict__ V, const float* __restrict__ ev,
                          const float* __restrict__ denom, const int* __restrict__ rowptr,
                          const int* __restrict__ eids, const int* __restrict__ src,
                          float* __restrict__ acc, int hbase, int G)
{
    constexpr int VEC = C / 64;
    using vecH = typename VecT<VEC>::T;
    int gi = blockIdx.x * blockDim.x + threadIdx.x;
    int n = gi >> 6, lane = threadIdx.x & 63;
    if (n >= NN) return;
    int beg = rowptr[n], end = rowptr[n + 1];
    float a[VEC];
    #pragma unroll
    for (int j = 0; j < VEC; ++j) a[j] = 0.f;
    for (int h = 0; h < G; ++h) {
        float rd = 1.f / (denom[(size_t)n * NHEAD + hbase + h] + 1e-16f) * (1.f / NHEAD);
        for (int i = beg; i < end; ++i) {
            int e = eids[i];
            int s = src[e];
            float coeff = ev[(size_t)e * NHEAD + hbase + h] * rd;
            vecH v = *(const vecH*)(V + (size_t)s * ((size_t)G * C) + h * C + lane * VEC);
            #pragma unroll
            for (int j = 0; j < VEC; ++j) a[j] += coeff * (float)v[j];
        }
    }
    float* ap = acc + (size_t)n * C + lane * VEC;
    #pragma unroll
    for (int j = 0; j < VEC; ++j) ap[j] += a[j];
}

__global__ void elu_k(float* __restrict__ x, int n) {
    int i = blockIdx.x * blockDim.x + threadIdx.x;
    if (i < n) { float v = x[i]; x[i] = v > 0.f ? v : expm1f(v); }
}
__global__ void elu_cvt(const float* __restrict__ in, _Float16* __restrict__ out, int n) {
    int i = blockIdx.x * blockDim.x + threadIdx.x;
    if (i < n) { float v = in[i]; v = v > 0.f ? v : expm1f(v); out[i] = (_Float16)v; }
}

// ---------------- fused global-attention pooling + final fc ----------------
// batch is SORTED -> one block (4 waves, 256 thr) per graph; zero atomics.
// Phase A: logits + block max.  B: exp+sum.  C: channel-per-thread weighted sum.
// D: out[b] = (acc/denom) @ Wf + bf  (block reduce per output).
__global__ __launch_bounds__(256) void pool_fused(
    const float* __restrict__ H2, const float* __restrict__ Wg,
    const float* __restrict__ bg, const int* __restrict__ batch,
    const float* __restrict__ Wf, const float* __restrict__ bf,
    float* __restrict__ glogit /*NN scratch*/, float* __restrict__ out)
{
    const int b = blockIdx.x;
    const int t = threadIdx.x, lane = t & 63, w = t >> 6;
    __shared__ int sbeg, send;
    __shared__ float sred[4];
    if (t == 0) {
        int lo = 0, hi = NN;
        while (lo < hi) { int mid = (lo + hi) >> 1; if (batch[mid] < b) lo = mid + 1; else hi = mid; }
        sbeg = lo;
        hi = NN;
        while (lo < hi) { int mid = (lo + hi) >> 1; if (batch[mid] < b + 1) lo = mid + 1; else hi = mid; }
        send = lo;
    }
    __syncthreads();
    const int beg = sbeg, end = send;
    const float bg0 = bg[0];

    // A: logits (one wave per node), running max
    float lmax = -INFINITY;
    for (int n = beg + w; n < end; n += 4) {
        float4 h = ((const float4*)(H2 + (size_t)n * C2))[lane];
        float4 wv = ((const float4*)Wg)[lane];
        float sum = h.x * wv.x + h.y * wv.y + h.z * wv.z + h.w * wv.w;
        #pragma unroll
        for (int off = 32; off; off >>= 1) sum += __shfl_xor(sum, off);
        sum += bg0;
        if (lane == 0) glogit[n] = sum;
        lmax = fmaxf(lmax, sum);
    }
    if (lane == 0) sred[w] = lmax;
    __syncthreads();
    float m = fmaxf(fmaxf(sred[0], sred[1]), fmaxf(sred[2], sred[3]));
    if (!isfinite(m)) m = 0.f;   // matches reference's finite-fix (empty graphs)
    __syncthreads();

    // B: e = exp(logit - m), denom = sum(e); store e back
    float ls = 0.f;
    for (int n = beg + t; n < end; n += 256) {
        float e = expf(glogit[n] - m);
        glogit[n] = e;
        ls += e;
    }
    #pragma unroll
    for (int off = 32; off; off >>= 1) ls += __shfl_xor(ls, off);
    if (lane == 0) sred[w] = ls;
    __syncthreads();
    const float denom = sred[0] + sred[1] + sred[2] + sred[3] + 1e-16f;
    __syncthreads();

    // C: thread t owns channel t
    float acc = 0.f;
    for (int n = beg; n < end; ++n)
        acc += glogit[n] * H2[(size_t)n * C2 + t];
    const float gc = acc / denom;

    // D: out[b][o] = sum_c gc_c * Wf[c][o] + bf[o]
    for (int o = 0; o < NOUT; ++o) {
        float p = gc * Wf[t * NOUT + o];
        #pragma unroll
        for (int off = 32; off; off >>= 1) p += __shfl_xor(p, off);
        __syncthreads();
        if (lane == 0) sred[w] = p;
        __syncthreads();
        if (t == 0) out[b * NOUT + o] = sred[0] + sred[1] + sred[2] + sred[3] + bf[o];
    }
}

extern "C" void kernel_launch(void* const* d_in, const int* in_sizes, int n_in,
                              void* d_out, int out_size, void* d_ws, size_t ws_size,
                              hipStream_t stream) {
    (void)in_sizes; (void)n_in; (void)out_size;
    const float* x     = (const float*)d_in[0];
    const int*   ei    = (const int*)  d_in[1];
    const int*   batch = (const int*)  d_in[2];
    const float* Wq1 = (const float*)d_in[3];  const float* bq1 = (const float*)d_in[4];
    const float* Wk1 = (const float*)d_in[5];  const float* bk1 = (const float*)d_in[6];
    const float* Wv1 = (const float*)d_in[7];  const float* bv1 = (const float*)d_in[8];
    const float* Ws1 = (const float*)d_in[9];  const float* bs1 = (const float*)d_in[10];
    const float* Wq2 = (const float*)d_in[11]; const float* bq2 = (const float*)d_in[12];
    const float* Wk2 = (const float*)d_in[13]; const float* bk2 = (const float*)d_in[14];
    const float* Wv2 = (const float*)d_in[15]; const float* bv2 = (const float*)d_in[16];
    const float* Ws2 = (const float*)d_in[17]; const float* bs2 = (const float*)d_in[18];
    const float* Wg  = (const float*)d_in[19]; const float* bg  = (const float*)d_in[20];
    const float* Wf  = (const float*)d_in[21]; const float* bf  = (const float*)d_in[22];

    const int* src = ei;
    const int* dst = ei + NE;

    // ---- workspace layout ----
    char* base = (char*)d_ws;
    size_t off = 0;
    auto alloc = [&](size_t bytes) -> char* {
        char* p = base + off;
        off = (off + bytes + 255) & ~(size_t)255;
        return p;
    };
    _Float16* xb   = (_Float16*)alloc((size_t)NN * FIN * 2);
    _Float16* wtq1 = (_Float16*)alloc((size_t)NHEAD * C1 * FIN * 2);
    _Float16* wtk1 = (_Float16*)alloc((size_t)NHEAD * C1 * FIN * 2);
    _Float16* wtv1 = (_Float16*)alloc((size_t)NHEAD * C1 * FIN * 2);
    _Float16* wts1 = (_Float16*)alloc((size_t)C1 * FIN * 2);
    _Float16* wtq2 = (_Float16*)alloc((size_t)NHEAD * C2 * C1 * 2);
    _Float16* wtk2 = (_Float16*)alloc((size_t)NHEAD * C2 * C1 * 2);
    _Float16* wtv2 = (_Float16*)alloc((size_t)NHEAD * C2 * C1 * 2);
    _Float16* wts2 = (_Float16*)alloc((size_t)C2 * C1 * 2);
    float* acc1 = (float*)alloc((size_t)NN * C1 * 4);
    _Float16* h1b = (_Float16*)alloc((size_t)NN * C1 * 2);
    float* alpha = (float*)alloc((size_t)NE * NHEAD * 4);
    float* ev    = (float*)alloc((size_t)NE * NHEAD * 4);
    unsigned* amaxU = (unsigned*)alloc((size_t)NN * NHEAD * 4);
    float* denom = (float*)alloc((size_t)NN * NHEAD * 4);
    int* deg    = (int*)alloc((size_t)NN * 4);
    int* rowptr = (int*)alloc((size_t)(NN + 1) * 4);
    int* cursor = (int*)alloc((size_t)NN * 4);
    int* eids   = (int*)alloc((size_t)NE * 4);
    float* g    = (float*)alloc((size_t)NB * C2 * 4);  // (unused now, kept for layout stability)
    size_t fixed_end = off;
    float* acc2 = acc1;  // alias: conv1 fp32 accum dead once h1b built
    (void)g;

    int G = 1;
    for (int cand = 8; cand >= 1; cand >>= 1) {
        size_t qk = (((size_t)NN * cand * C1 * 2) + 255) & ~(size_t)255;
        if (fixed_end + 2 * qk <= ws_size) { G = cand; break; }
        if (cand == 1) G = 1;
    }
    size_t qk_bytes = (((size_t)NN * G * C1 * 2) + 255) & ~(size_t)255;
    _Float16* Qbuf = (_Float16*)(base + fixed_end);
    _Float16* Kbuf = (_Float16*)(base + fixed_end + qk_bytes);
    _Float16* Vbuf = Qbuf;

    const dim3 blk(256);
    const float sc1 = 1.0f / sqrtf((float)C1);
    const float sc2 = 1.0f / sqrtf((float)C2);
    const int edge_blocks = (NE * 64) / 256;
    const int node_blocks = (NN * 64) / 256;
    const int gy = (NN + 127) / 128;

    // ---- conversions ----
    cvt_f16<<<((size_t)NN * FIN + 255) / 256, blk, 0, stream>>>(x, xb, NN * FIN);
    {
        dim3 tb(32, 8);
        transpose_cvt<<<dim3(NHEAD * C1 / 32, FIN / 32), tb, 0, stream>>>(Wq1, wtq1, FIN, NHEAD * C1);
        transpose_cvt<<<dim3(NHEAD * C1 / 32, FIN / 32), tb, 0, stream>>>(Wk1, wtk1, FIN, NHEAD * C1);
        transpose_cvt<<<dim3(NHEAD * C1 / 32, FIN / 32), tb, 0, stream>>>(Wv1, wtv1, FIN, NHEAD * C1);
        transpose_cvt<<<dim3(C1 / 32, FIN / 32),         tb, 0, stream>>>(Ws1, wts1, FIN, C1);
        transpose_cvt<<<dim3(NHEAD * C2 / 32, C1 / 32),  tb, 0, stream>>>(Wq2, wtq2, C1, NHEAD * C2);
        transpose_cvt<<<dim3(NHEAD * C2 / 32, C1 / 32),  tb, 0, stream>>>(Wk2, wtk2, C1, NHEAD * C2);
        transpose_cvt<<<dim3(NHEAD * C2 / 32, C1 / 32),  tb, 0, stream>>>(Wv2, wtv2, C1, NHEAD * C2);
        transpose_cvt<<<dim3(C2 / 32, C1 / 32),          tb, 0, stream>>>(Ws2, wts2, C1, C2);
    }

    // ---- CSR by dst ----
    zero_i32<<<(NN + 255) / 256, blk, 0, stream>>>(deg, NN);
    hist_dst<<<(NE + 255) / 256, blk, 0, stream>>>(dst, deg);
    scan_deg<<<1, blk, 0, stream>>>(deg, rowptr, cursor, NN);
    scatter_edges<<<(NE + 255) / 256, blk, 0, stream>>>(dst, cursor, eids);

    // ================ conv1 ================
    gemm_tn<false><<<dim3(C1 / 128, gy), blk, 0, stream>>>(xb, wts1, bs1, acc1, C1, NN, FIN);
    init_seg<<<(NN * NHEAD + 255) / 256, blk, 0, stream>>>(amaxU, denom, NN * NHEAD);
    for (int hb = 0; hb < NHEAD; hb += G) {
        gemm_tn<true><<<dim3(G * C1 / 128, gy), blk, 0, stream>>>(
            xb, wtq1 + (size_t)hb * C1 * FIN, bq1 + hb * C1, Qbuf, G * C1, NN, FIN);
        gemm_tn<true><<<dim3(G * C1 / 128, gy), blk, 0, stream>>>(
            xb, wtk1 + (size_t)hb * C1 * FIN, bk1 + hb * C1, Kbuf, G * C1, NN, FIN);
        edge_alpha_f<C1><<<edge_blocks, blk, 0, stream>>>(Qbuf, Kbuf, src, dst, alpha, amaxU,
                                                          sc1, hb, G);
    }
    edge_expsum<<<(NE * NHEAD + 255) / 256, blk, 0, stream>>>(alpha, dst, amaxU, ev, denom);
    for (int hb = 0; hb < NHEAD; hb += G) {
        gemm_tn<true><<<dim3(G * C1 / 128, gy), blk, 0, stream>>>(
            xb, wtv1 + (size_t)hb * C1 * FIN, bv1 + hb * C1, Vbuf, G * C1, NN, FIN);
        node_aggr<C1><<<node_blocks, blk, 0, stream>>>(Vbuf, ev, denom, rowptr, eids, src,
                                                       acc1, hb, G);
    }
    elu_cvt<<<((size_t)NN * C1 + 255) / 256, blk, 0, stream>>>(acc1, h1b, NN * C1);

    // ================ conv2 ================
    gemm_tn<false><<<dim3(C2 / 128, gy), blk, 0, stream>>>(h1b, wts2, bs2, acc2, C2, NN, C1);
    init_seg<<<(NN * NHEAD + 255) / 256, blk, 0, stream>>>(amaxU, denom, NN * NHEAD);
    for (int hb = 0; hb < NHEAD; hb += G) {
        gemm_tn<true><<<dim3(G * C2 / 128, gy), blk, 0, stream>>>(
            h1b, wtq2 + (size_t)hb * C2 * C1, bq2 + hb * C2, Qbuf, G * C2, NN, C1);
        gemm_tn<true><<<dim3(G * C2 / 128, gy), blk, 0, stream>>>(
            h1b, wtk2 + (size_t)hb * C2 * C1, bk2 + hb * C2, Kbuf, G * C2, NN, C1);
        edge_alpha_f<C2><<<edge_blocks, blk, 0, stream>>>(Qbuf, Kbuf, src, dst, alpha, amaxU,
                                                          sc2, hb, G);
    }
    edge_expsum<<<(NE * NHEAD + 255) / 256, blk, 0, stream>>>(alpha, dst, amaxU, ev, denom);
    for (int hb = 0; hb < NHEAD; hb += G) {
        gemm_tn<true><<<dim3(G * C2 / 128, gy), blk, 0, stream>>>(
            h1b, wtv2 + (size_t)hb * C2 * C1, bv2 + hb * C2, Vbuf, G * C2, NN, C1);
        node_aggr<C2><<<node_blocks, blk, 0, stream>>>(Vbuf, ev, denom, rowptr, eids, src,
                                                       acc2, hb, G);
    }
    elu_k<<<((size_t)NN * C2 + 255) / 256, blk, 0, stream>>>(acc2, NN * C2);

    // ================ fused pooling + fc (no atomics; batch is sorted) ================
    pool_fused<<<NB, blk, 0, stream>>>(acc2, Wg, bg, batch, Wf, bf, alpha, (float*)d_out);
}